// Round 8
// baseline (50.945 us; speedup 1.0000x reference)
//
#include <hip/hip_runtime.h>

#define NTYPES 216
#define NPIX   4096
#define KD     576      // C*3*3
#define ROWLEN 577      // KD + bias
#define NPC    32       // pixels per block-iteration
#define PSTR   640      // u16 elements per pixel row in Pl (576 data + 64 shift pad)

typedef __attribute__((ext_vector_type(8))) short short8;
typedef __attribute__((ext_vector_type(4))) float f32x4;
typedef __attribute__((ext_vector_type(4), aligned(4))) float f32x4u;  // 4B-aligned vector load
typedef __attribute__((ext_vector_type(8))) unsigned short u16x8;
typedef __attribute__((ext_vector_type(4))) unsigned short u16x4;

static __device__ __forceinline__ unsigned short f2bf(float f) {
    unsigned u = __builtin_bit_cast(unsigned, f);
    unsigned r = (u + 0x7FFFu + ((u >> 16) & 1u)) >> 16;  // RNE
    return (unsigned short)r;
}

// ---------- K1: counting sort with parallel scan (1 block) ----------
__global__ __launch_bounds__(256) void sort_kernel(
        const int* __restrict__ buckets, int* __restrict__ offsets,
        int* __restrict__ sorted) {
    __shared__ int cnt[256];
    __shared__ int pre[256];
    int tid = threadIdx.x;
    cnt[tid] = 0;
    __syncthreads();
    for (int i = tid; i < NPIX; i += 256) atomicAdd(&cnt[buckets[i]], 1);
    __syncthreads();
    int v = cnt[tid];
    pre[tid] = v;
    __syncthreads();
    #pragma unroll
    for (int s = 1; s < 256; s <<= 1) {
        int add = (tid >= s) ? pre[tid - s] : 0;
        __syncthreads();
        pre[tid] += add;
        __syncthreads();
    }
    int excl = pre[tid] - v;            // exclusive prefix
    if (tid <= NTYPES) offsets[tid] = excl;   // offsets[216] == 4096
    cnt[tid] = excl;                    // running cursors
    __syncthreads();
    for (int i = tid; i < NPIX; i += 256) {
        int b = buckets[i];
        sorted[atomicAdd(&cnt[b], 1)] = i;
    }
}

// ---------- K2: grouped 3x3 conv + bias + relu -> h (bf16) ----------
__global__ __launch_bounds__(256) void body1_kernel(
        const float* __restrict__ x, const float* __restrict__ w1,
        const float* __restrict__ b1, unsigned short* __restrict__ hbf) {
    int tid = threadIdx.x;
    int flat = blockIdx.x * 256 + tid;   // c(6) | y(6) | x4(4)
    int x4 = flat & 15;
    int y  = (flat >> 4) & 63;
    int c  = flat >> 10;                  // block-uniform
    int g  = c >> 4;
    const float* wrow = w1 + c * 144;
    float o0, o1, o2, o3;
    o0 = o1 = o2 = o3 = b1[c];
    #pragma unroll
    for (int ci = 0; ci < 16; ++ci) {
        const float* xp = x + (g * 16 + ci) * 4096;
        #pragma unroll
        for (int dy = 0; dy < 3; ++dy) {
            int yy = y + dy - 1;
            if (yy < 0 || yy > 63) continue;
            const float* row = xp + yy * 64 + x4 * 4;
            f32x4 mm = *(const f32x4*)row;
            float xl = (x4 > 0)  ? row[-1] : 0.f;
            float xr = (x4 < 15) ? row[4]  : 0.f;
            float wa = wrow[ci * 9 + dy * 3 + 0];
            float wb = wrow[ci * 9 + dy * 3 + 1];
            float wc = wrow[ci * 9 + dy * 3 + 2];
            o0 = fmaf(wa, xl,    fmaf(wb, mm[0], fmaf(wc, mm[1], o0)));
            o1 = fmaf(wa, mm[0], fmaf(wb, mm[1], fmaf(wc, mm[2], o1)));
            o2 = fmaf(wa, mm[1], fmaf(wb, mm[2], fmaf(wc, mm[3], o2)));
            o3 = fmaf(wa, mm[2], fmaf(wb, mm[3], fmaf(wc, xr,    o3)));
        }
    }
    u16x4 r16;
    r16[0] = f2bf(fmaxf(o0, 0.f));
    r16[1] = f2bf(fmaxf(o1, 0.f));
    r16[2] = f2bf(fmaxf(o2, 0.f));
    r16[3] = f2bf(fmaxf(o3, 0.f));
    *(u16x4*)&hbf[flat * 4] = r16;
}

// ---------- K3: per-bucket MFMA GEMM, W streamed f32->bf16 regs once per block ----------
__global__ __launch_bounds__(512) void dyn_kernel(
        const unsigned short* __restrict__ hbf, const float* __restrict__ emb,
        const float* __restrict__ w2, const float* __restrict__ b2,
        const float* __restrict__ x, const int* __restrict__ offsets,
        const int* __restrict__ sorted, float* __restrict__ out) {

    __shared__ alignas(16) unsigned short Pl[NPC * PSTR];  // 40960 B patches (bf16, shifted rows)
    __shared__ alignas(16) unsigned short Dl[NPC * 72];    //  4608 B intermediate
    __shared__ alignas(16) unsigned short w2l[64 * 72];    //  9216 B 1x1 weights bf16
    __shared__ int pixs[NPC];

    int t = blockIdx.x;
    int start = offsets[t];
    int n = offsets[t + 1] - start;
    if (n <= 0) return;

    int tid  = threadIdx.x;
    int lane = tid & 63;
    int wv   = tid >> 6;
    int m    = wv & 3;          // M-tile (16 out channels)
    int ph   = wv >> 2;         // pixel half
    int ra   = lane & 15;
    int kg   = lane >> 4;

    const float* eb = emb + (size_t)t * (64 * ROWLEN);

    // ---- W: stream f32 rows with WIDE loads (runs of 8 consecutive floats), cvt once ----
    const float* wlb = eb + (m * 16 + ra) * ROWLEN + kg * 8;
    u16x8 Wr[9][2];
    #pragma unroll
    for (int ck = 0; ck < 9; ++ck) {
        f32x4u a0 = *(const f32x4u*)(wlb + ck * 64);
        f32x4u a1 = *(const f32x4u*)(wlb + ck * 64 + 4);
        f32x4u b0 = *(const f32x4u*)(wlb + ck * 64 + 32);
        f32x4u b1 = *(const f32x4u*)(wlb + ck * 64 + 36);
        u16x8 w0, w1;
        #pragma unroll
        for (int j = 0; j < 4; ++j) {
            w0[j]     = f2bf(a0[j]);
            w0[j + 4] = f2bf(a1[j]);
            w1[j]     = f2bf(b0[j]);
            w1[j + 4] = f2bf(b1[j]);
        }
        Wr[ck][0] = w0;
        Wr[ck][1] = w1;
    }
    // per-out-channel dynamic bias (iteration-invariant)
    float bias0 = eb[(m * 16 + kg * 4 + 0) * ROWLEN + KD];
    float bias1 = eb[(m * 16 + kg * 4 + 1) * ROWLEN + KD];
    float bias2 = eb[(m * 16 + kg * 4 + 2) * ROWLEN + KD];
    float bias3 = eb[(m * 16 + kg * 4 + 3) * ROWLEN + KD];

    // stage w2 -> bf16 LDS (once)
    {
        int o = tid >> 3, i8 = (tid & 7) * 8;
        const float* src = w2 + o * 64 + i8;
        u16x8 v;
        #pragma unroll
        for (int j = 0; j < 8; ++j) v[j] = f2bf(src[j]);
        *(u16x8*)&w2l[o * 72 + i8] = v;
    }

    const unsigned short* pB = Pl + (ph * 16 + ra) * PSTR + (ra & 7) * 8 + kg * 8;

    // gather roles
    int gp = tid >> 4;          // pixel 0..31
    int gk = tid & 15;
    unsigned short* pdst = Pl + gp * PSTR + (gp & 7) * 8;

    for (int base = 0; base < n; base += NPC) {
        __syncthreads();   // protect pixs/Pl/Dl from previous iteration's readers
        if (tid < NPC) pixs[tid] = (base + tid < n) ? sorted[start + base + tid] : -1;
        __syncthreads();

        // ---- stage full patch tile P[32 px][576 k] bf16 from hbf ----
        {
            int pixel = pixs[gp];
            int py = pixel >> 6, px = pixel & 63;
            #pragma unroll
            for (int pass = 0; pass < 9; ++pass) {
                int k0 = pass * 64 + gk * 4;
                u16x4 v;
                #pragma unroll
                for (int j = 0; j < 4; ++j) {
                    int k = k0 + j;
                    int cch = k / 9, r9 = k - cch * 9;
                    int dy = r9 / 3, dx = r9 - dy * 3;
                    unsigned short bits = 0;
                    if (pixel >= 0) {
                        int yy = py + dy - 1, xx = px + dx - 1;
                        if (yy >= 0 && yy < 64 && xx >= 0 && xx < 64)
                            bits = hbf[cch * 4096 + yy * 64 + xx];
                    }
                    v[j] = bits;
                }
                *(u16x4*)(pdst + k0) = v;
            }
        }
        __syncthreads();   // P ready (also covers w2l on first iteration)

        // ---- K-loop: 18 ds_read_b128 + 18 MFMA, zero conversion ----
        f32x4 acc = {0.f, 0.f, 0.f, 0.f};
        #pragma unroll
        for (int ck = 0; ck < 9; ++ck) {
            #pragma unroll
            for (int ks = 0; ks < 2; ++ks) {
                u16x8 bv = *(const u16x8*)(pB + ck * 64 + ks * 32);
                acc = __builtin_amdgcn_mfma_f32_16x16x32_bf16(
                          __builtin_bit_cast(short8, Wr[ck][ks]),
                          __builtin_bit_cast(short8, bv), acc, 0, 0, 0);
            }
        }

        // ---- bias + relu -> Dl (bf16) ----
        {
            int pi = ph * 16 + ra;
            u16x4 dv;
            dv[0] = f2bf(fmaxf(acc[0] + bias0, 0.f));
            dv[1] = f2bf(fmaxf(acc[1] + bias1, 0.f));
            dv[2] = f2bf(fmaxf(acc[2] + bias2, 0.f));
            dv[3] = f2bf(fmaxf(acc[3] + bias3, 0.f));
            *(u16x4*)&Dl[pi * 72 + m * 16 + kg * 4] = dv;
        }
        __syncthreads();   // D ready

        // ---- GEMM2: 1x1 conv (K=64) ----
        f32x4 acc2 = {0.f, 0.f, 0.f, 0.f};
        #pragma unroll
        for (int ks = 0; ks < 2; ++ks) {
            u16x8 a2  = *(const u16x8*)&w2l[(m * 16 + ra) * 72 + ks * 32 + kg * 8];
            u16x8 b2v = *(const u16x8*)&Dl[(ph * 16 + ra) * 72 + ks * 32 + kg * 8];
            acc2 = __builtin_amdgcn_mfma_f32_16x16x32_bf16(
                       __builtin_bit_cast(short8, a2),
                       __builtin_bit_cast(short8, b2v), acc2, 0, 0, 0);
        }

        // ---- epilogue: + b2 + residual, relu, store ----
        {
            int pi = ph * 16 + ra;
            int pixel = pixs[pi];
            if (pixel >= 0) {
                int o0 = m * 16 + kg * 4;
                #pragma unroll
                for (int j = 0; j < 4; ++j) {
                    int o = o0 + j;
                    float v = acc2[j] + b2[o] + x[o * 4096 + pixel];
                    out[o * 4096 + pixel] = fmaxf(v, 0.f);
                }
            }
        }
    }
}

extern "C" void kernel_launch(void* const* d_in, const int* in_sizes, int n_in,
                              void* d_out, int out_size, void* d_ws, size_t ws_size,
                              hipStream_t stream) {
    const float* x       = (const float*)d_in[0];
    const int*   buckets = (const int*)d_in[1];
    const float* w1      = (const float*)d_in[2];
    const float* b1      = (const float*)d_in[3];
    const float* emb     = (const float*)d_in[4];
    const float* w2      = (const float*)d_in[5];
    const float* b2      = (const float*)d_in[6];
    float* out = (float*)d_out;

    char* ws = (char*)d_ws;
    unsigned short* hbf = (unsigned short*)ws;              // 512 KB
    int*   offsets      = (int*)(ws + (1 << 20));           // 217 ints
    int*   sorted       = (int*)(ws + (1 << 20) + 4096);    // 4096 ints

    sort_kernel<<<1, 256, 0, stream>>>(buckets, offsets, sorted);
    body1_kernel<<<256, 256, 0, stream>>>(x, w1, b1, hbf);
    dyn_kernel<<<NTYPES, 512, 0, stream>>>(hbf, emb, w2, b2, x, offsets, sorted, out);
}

// Round 9
// 41.993 us; speedup vs baseline: 1.2132x; 1.2132x over previous
//
#include <hip/hip_runtime.h>

#define NTYPES 216
#define NPIX   4096
#define KD     576      // C*3*3
#define ROWLEN 577      // KD + bias
#define NPC    32       // pixels per block-iteration
#define PSTR   640      // u16 elements per pixel row in Pl (576 data + 64 shift pad)

#define EMB_BF_OFF (2u << 20)                          // ws byte offset of emb_bf
#define BIAS_OFF   (EMB_BF_OFF + NTYPES * 36864u * 2u) // ws byte offset of bias (f32)

#define CONV_BLOCKS 512
#define TOTAL_CHUNKS (NTYPES * 36928 / 4)   // 1,994,112 f32x4 chunks

typedef __attribute__((ext_vector_type(8))) short short8;
typedef __attribute__((ext_vector_type(4))) float f32x4;
typedef __attribute__((ext_vector_type(8))) unsigned short u16x8;
typedef __attribute__((ext_vector_type(4))) unsigned short u16x4;

static __device__ __forceinline__ unsigned short f2bf(float f) {
    unsigned u = __builtin_bit_cast(unsigned, f);
    unsigned r = (u + 0x7FFFu + ((u >> 16) & 1u)) >> 16;  // RNE
    return (unsigned short)r;
}

// ---------- Kernel A ----------
// blocks 0..255   : grouped 3x3 conv + bias + relu -> h (bf16)
// block  256      : counting-sort pixels by bucket (parallel scan)
// blocks 257..768 : flat coalesced wide emb -> bf16 conversion + bias extraction
__global__ __launch_bounds__(256) void prep_kernel(
        const float* __restrict__ x, const float* __restrict__ w1,
        const float* __restrict__ b1, const int* __restrict__ buckets,
        const float* __restrict__ emb,
        unsigned short* __restrict__ hbf, int* __restrict__ offsets,
        int* __restrict__ sorted, unsigned short* __restrict__ emb_bf,
        float* __restrict__ bias_ws) {
    int tid = threadIdx.x;
    if (blockIdx.x > 256) {
        // ---- emb conversion: flat grid-stride, f32x4 loads (coalesced + wide) ----
        int gid = (blockIdx.x - 257) * 256 + tid;
        for (int i = gid; i < TOTAL_CHUNKS; i += CONV_BLOCKS * 256) {
            int idx = i * 4;
            int t = idx / 36928;
            int local = idx - t * 36928;
            f32x4 v = *(const f32x4*)(emb + (size_t)idx);
            #pragma unroll
            for (int j = 0; j < 4; ++j) {
                int lj = local + j;
                int r = lj / ROWLEN;
                int c = lj - r * ROWLEN;
                if (c < KD) emb_bf[t * 36864 + r * 576 + c] = f2bf(v[j]);
                else        bias_ws[t * 64 + r] = v[j];
            }
        }
        return;
    }
    if (blockIdx.x == 256) {
        // ---- counting sort with parallel scan ----
        __shared__ int cnt[256];
        __shared__ int pre[256];
        cnt[tid] = 0;
        __syncthreads();
        for (int i = tid; i < NPIX; i += 256) atomicAdd(&cnt[buckets[i]], 1);
        __syncthreads();
        int v = cnt[tid];
        pre[tid] = v;
        __syncthreads();
        #pragma unroll
        for (int s = 1; s < 256; s <<= 1) {
            int add = (tid >= s) ? pre[tid - s] : 0;
            __syncthreads();
            pre[tid] += add;
            __syncthreads();
        }
        int excl = pre[tid] - v;            // exclusive prefix
        if (tid <= NTYPES) offsets[tid] = excl;
        cnt[tid] = excl;
        __syncthreads();
        for (int i = tid; i < NPIX; i += 256) {
            int b = buckets[i];
            sorted[atomicAdd(&cnt[b], 1)] = i;
        }
        return;
    }
    // ---- body1: grouped conv, 4 px/thread, store bf16 ----
    int flat = blockIdx.x * 256 + tid;   // c(6) | y(6) | x4(4)
    int x4 = flat & 15;
    int y  = (flat >> 4) & 63;
    int c  = flat >> 10;                  // block-uniform
    int g  = c >> 4;
    const float* wrow = w1 + c * 144;
    float o0, o1, o2, o3;
    o0 = o1 = o2 = o3 = b1[c];
    #pragma unroll
    for (int ci = 0; ci < 16; ++ci) {
        const float* xp = x + (g * 16 + ci) * 4096;
        #pragma unroll
        for (int dy = 0; dy < 3; ++dy) {
            int yy = y + dy - 1;
            if (yy < 0 || yy > 63) continue;
            const float* row = xp + yy * 64 + x4 * 4;
            f32x4 mm = *(const f32x4*)row;
            float xl = (x4 > 0)  ? row[-1] : 0.f;
            float xr = (x4 < 15) ? row[4]  : 0.f;
            float wa = wrow[ci * 9 + dy * 3 + 0];
            float wb = wrow[ci * 9 + dy * 3 + 1];
            float wc = wrow[ci * 9 + dy * 3 + 2];
            o0 = fmaf(wa, xl,    fmaf(wb, mm[0], fmaf(wc, mm[1], o0)));
            o1 = fmaf(wa, mm[0], fmaf(wb, mm[1], fmaf(wc, mm[2], o1)));
            o2 = fmaf(wa, mm[1], fmaf(wb, mm[2], fmaf(wc, mm[3], o2)));
            o3 = fmaf(wa, mm[2], fmaf(wb, mm[3], fmaf(wc, xr,    o3)));
        }
    }
    u16x4 r16;
    r16[0] = f2bf(fmaxf(o0, 0.f));
    r16[1] = f2bf(fmaxf(o1, 0.f));
    r16[2] = f2bf(fmaxf(o2, 0.f));
    r16[3] = f2bf(fmaxf(o3, 0.f));
    *(u16x4*)&hbf[flat * 4] = r16;
}

// ---------- Kernel B: per-bucket MFMA GEMM, W fully register-resident ----------
__global__ __launch_bounds__(512) void dyn_kernel(
        const unsigned short* __restrict__ hbf, const unsigned short* __restrict__ emb_bf,
        const float* __restrict__ bias_ws,
        const float* __restrict__ w2, const float* __restrict__ b2,
        const float* __restrict__ x, const int* __restrict__ offsets,
        const int* __restrict__ sorted, float* __restrict__ out) {

    __shared__ alignas(16) unsigned short Pl[NPC * PSTR];  // 40960 B patches (bf16, shifted rows)
    __shared__ alignas(16) unsigned short Dl[NPC * 72];    //  4608 B intermediate
    __shared__ alignas(16) unsigned short w2l[64 * 72];    //  9216 B 1x1 weights bf16
    __shared__ int pixs[NPC];

    int t = blockIdx.x;
    int start = offsets[t];
    int n = offsets[t + 1] - start;
    if (n <= 0) return;

    int tid  = threadIdx.x;
    int lane = tid & 63;
    int wv   = tid >> 6;
    int m    = wv & 3;          // M-tile (16 out channels)
    int ph   = wv >> 2;         // pixel half
    int ra   = lane & 15;
    int kg   = lane >> 4;

    // ---- W: 9 chunks x 2 k-steps, fully prefetched into 72 VGPRs (coalesced dwordx4) ----
    const unsigned short* wlb = emb_bf + (size_t)t * 36864 + (m * 16 + ra) * 576 + kg * 8;
    u16x8 Wr[9][2];
    #pragma unroll
    for (int ck = 0; ck < 9; ++ck) {
        Wr[ck][0] = *(const u16x8*)(wlb + ck * 64);
        Wr[ck][1] = *(const u16x8*)(wlb + ck * 64 + 32);
    }
    // per-out-channel dynamic bias (iteration-invariant)
    const float* bl = bias_ws + t * 64 + m * 16 + kg * 4;
    float bias0 = bl[0], bias1 = bl[1], bias2 = bl[2], bias3 = bl[3];

    // stage w2 -> bf16 LDS (once)
    {
        int o = tid >> 3, i8 = (tid & 7) * 8;
        const float* src = w2 + o * 64 + i8;
        u16x8 v;
        #pragma unroll
        for (int j = 0; j < 8; ++j) v[j] = f2bf(src[j]);
        *(u16x8*)&w2l[o * 72 + i8] = v;
    }

    const unsigned short* pB = Pl + (ph * 16 + ra) * PSTR + (ra & 7) * 8 + kg * 8;

    // gather roles
    int gp = tid >> 4;          // pixel 0..31
    int gk = tid & 15;
    unsigned short* pdst = Pl + gp * PSTR + (gp & 7) * 8;

    for (int base = 0; base < n; base += NPC) {
        __syncthreads();   // protect pixs/Pl/Dl from previous iteration's readers
        if (tid < NPC) pixs[tid] = (base + tid < n) ? sorted[start + base + tid] : -1;
        __syncthreads();

        // ---- stage full patch tile P[32 px][576 k] bf16 from hbf ----
        {
            int pixel = pixs[gp];
            int py = pixel >> 6, px = pixel & 63;
            #pragma unroll
            for (int pass = 0; pass < 9; ++pass) {
                int k0 = pass * 64 + gk * 4;
                u16x4 v;
                #pragma unroll
                for (int j = 0; j < 4; ++j) {
                    int k = k0 + j;
                    int cch = k / 9, r9 = k - cch * 9;
                    int dy = r9 / 3, dx = r9 - dy * 3;
                    unsigned short bits = 0;
                    if (pixel >= 0) {
                        int yy = py + dy - 1, xx = px + dx - 1;
                        if (yy >= 0 && yy < 64 && xx >= 0 && xx < 64)
                            bits = hbf[cch * 4096 + yy * 64 + xx];
                    }
                    v[j] = bits;
                }
                *(u16x4*)(pdst + k0) = v;
            }
        }
        __syncthreads();   // P ready (also covers w2l on first iteration)

        // ---- K-loop: 18 ds_read_b128 + 18 MFMA, zero conversion ----
        f32x4 acc = {0.f, 0.f, 0.f, 0.f};
        #pragma unroll
        for (int ck = 0; ck < 9; ++ck) {
            #pragma unroll
            for (int ks = 0; ks < 2; ++ks) {
                u16x8 bv = *(const u16x8*)(pB + ck * 64 + ks * 32);
                acc = __builtin_amdgcn_mfma_f32_16x16x32_bf16(
                          __builtin_bit_cast(short8, Wr[ck][ks]),
                          __builtin_bit_cast(short8, bv), acc, 0, 0, 0);
            }
        }

        // ---- bias + relu -> Dl (bf16) ----
        {
            int pi = ph * 16 + ra;
            u16x4 dv;
            dv[0] = f2bf(fmaxf(acc[0] + bias0, 0.f));
            dv[1] = f2bf(fmaxf(acc[1] + bias1, 0.f));
            dv[2] = f2bf(fmaxf(acc[2] + bias2, 0.f));
            dv[3] = f2bf(fmaxf(acc[3] + bias3, 0.f));
            *(u16x4*)&Dl[pi * 72 + m * 16 + kg * 4] = dv;
        }
        __syncthreads();   // D ready

        // ---- GEMM2: 1x1 conv (K=64) ----
        f32x4 acc2 = {0.f, 0.f, 0.f, 0.f};
        #pragma unroll
        for (int ks = 0; ks < 2; ++ks) {
            u16x8 a2  = *(const u16x8*)&w2l[(m * 16 + ra) * 72 + ks * 32 + kg * 8];
            u16x8 b2v = *(const u16x8*)&Dl[(ph * 16 + ra) * 72 + ks * 32 + kg * 8];
            acc2 = __builtin_amdgcn_mfma_f32_16x16x32_bf16(
                       __builtin_bit_cast(short8, a2),
                       __builtin_bit_cast(short8, b2v), acc2, 0, 0, 0);
        }

        // ---- epilogue: + b2 + residual, relu, store ----
        {
            int pi = ph * 16 + ra;
            int pixel = pixs[pi];
            if (pixel >= 0) {
                int o0 = m * 16 + kg * 4;
                #pragma unroll
                for (int j = 0; j < 4; ++j) {
                    int o = o0 + j;
                    float v = acc2[j] + b2[o] + x[o * 4096 + pixel];
                    out[o * 4096 + pixel] = fmaxf(v, 0.f);
                }
            }
        }
    }
}

extern "C" void kernel_launch(void* const* d_in, const int* in_sizes, int n_in,
                              void* d_out, int out_size, void* d_ws, size_t ws_size,
                              hipStream_t stream) {
    const float* x       = (const float*)d_in[0];
    const int*   buckets = (const int*)d_in[1];
    const float* w1      = (const float*)d_in[2];
    const float* b1      = (const float*)d_in[3];
    const float* emb     = (const float*)d_in[4];
    const float* w2      = (const float*)d_in[5];
    const float* b2      = (const float*)d_in[6];
    float* out = (float*)d_out;

    char* ws = (char*)d_ws;
    unsigned short* hbf    = (unsigned short*)ws;                // 512 KB
    int*   offsets         = (int*)(ws + (1 << 20));             // 217 ints
    int*   sorted          = (int*)(ws + (1 << 20) + 4096);      // 4096 ints
    unsigned short* emb_bf = (unsigned short*)(ws + EMB_BF_OFF); // ~15.9 MB
    float* bias_ws         = (float*)(ws + BIAS_OFF);            // 55 KB

    prep_kernel<<<257 + CONV_BLOCKS, 256, 0, stream>>>(
        x, w1, b1, buckets, emb, hbf, offsets, sorted, emb_bf, bias_ws);
    dyn_kernel<<<NTYPES, 512, 0, stream>>>(hbf, emb_bf, bias_ws, w2, b2, x,
                                           offsets, sorted, out);
}

// Round 10
// 37.618 us; speedup vs baseline: 1.3543x; 1.1163x over previous
//
#include <hip/hip_runtime.h>

#define NTYPES 216
#define NPIX   4096
#define KD     576      // C*3*3
#define ROWLEN 577      // KD + bias
#define NPC    32       // pixels per block-iteration
#define PSTR   640      // u16 elements per LDS row (576 data + 64 shift pad)

typedef __attribute__((ext_vector_type(8))) short short8;
typedef __attribute__((ext_vector_type(4))) float f32x4;
typedef __attribute__((ext_vector_type(4), aligned(4))) float f32x4u;  // 4B-aligned
typedef __attribute__((ext_vector_type(8))) unsigned short u16x8;
typedef __attribute__((ext_vector_type(4))) unsigned short u16x4;

static __device__ __forceinline__ unsigned short f2bf(float f) {
    unsigned u = __builtin_bit_cast(unsigned, f);
    unsigned r = (u + 0x7FFFu + ((u >> 16) & 1u)) >> 16;  // RNE
    return (unsigned short)r;
}

// ---------- Kernel A: blocks 0..255 grouped conv -> h (bf16); block 256 sort ----------
__global__ __launch_bounds__(256) void prep_kernel(
        const float* __restrict__ x, const float* __restrict__ w1,
        const float* __restrict__ b1, const int* __restrict__ buckets,
        unsigned short* __restrict__ hbf, int* __restrict__ offsets,
        int* __restrict__ sorted) {
    int tid = threadIdx.x;
    if (blockIdx.x == 256) {
        // ---- counting sort with parallel scan ----
        __shared__ int cnt[256];
        __shared__ int pre[256];
        cnt[tid] = 0;
        __syncthreads();
        for (int i = tid; i < NPIX; i += 256) atomicAdd(&cnt[buckets[i]], 1);
        __syncthreads();
        int v = cnt[tid];
        pre[tid] = v;
        __syncthreads();
        #pragma unroll
        for (int s = 1; s < 256; s <<= 1) {
            int add = (tid >= s) ? pre[tid - s] : 0;
            __syncthreads();
            pre[tid] += add;
            __syncthreads();
        }
        int excl = pre[tid] - v;            // exclusive prefix
        if (tid <= NTYPES) offsets[tid] = excl;
        cnt[tid] = excl;
        __syncthreads();
        for (int i = tid; i < NPIX; i += 256) {
            int b = buckets[i];
            sorted[atomicAdd(&cnt[b], 1)] = i;
        }
        return;
    }
    // ---- body1: grouped conv, 4 px/thread, store bf16 ----
    int flat = blockIdx.x * 256 + tid;   // c(6) | y(6) | x4(4)
    int x4 = flat & 15;
    int y  = (flat >> 4) & 63;
    int c  = flat >> 10;                  // block-uniform
    int g  = c >> 4;
    const float* wrow = w1 + c * 144;
    float o0, o1, o2, o3;
    o0 = o1 = o2 = o3 = b1[c];
    #pragma unroll
    for (int ci = 0; ci < 16; ++ci) {
        const float* xp = x + (g * 16 + ci) * 4096;
        #pragma unroll
        for (int dy = 0; dy < 3; ++dy) {
            int yy = y + dy - 1;
            if (yy < 0 || yy > 63) continue;
            const float* row = xp + yy * 64 + x4 * 4;
            f32x4 mm = *(const f32x4*)row;
            float xl = (x4 > 0)  ? row[-1] : 0.f;
            float xr = (x4 < 15) ? row[4]  : 0.f;
            float wa = wrow[ci * 9 + dy * 3 + 0];
            float wb = wrow[ci * 9 + dy * 3 + 1];
            float wc = wrow[ci * 9 + dy * 3 + 2];
            o0 = fmaf(wa, xl,    fmaf(wb, mm[0], fmaf(wc, mm[1], o0)));
            o1 = fmaf(wa, mm[0], fmaf(wb, mm[1], fmaf(wc, mm[2], o1)));
            o2 = fmaf(wa, mm[1], fmaf(wb, mm[2], fmaf(wc, mm[3], o2)));
            o3 = fmaf(wa, mm[2], fmaf(wb, mm[3], fmaf(wc, xr,    o3)));
        }
    }
    u16x4 r16;
    r16[0] = f2bf(fmaxf(o0, 0.f));
    r16[1] = f2bf(fmaxf(o1, 0.f));
    r16[2] = f2bf(fmaxf(o2, 0.f));
    r16[3] = f2bf(fmaxf(o3, 0.f));
    *(u16x4*)&hbf[flat * 4] = r16;
}

// ---------- Kernel B: per-bucket MFMA GEMM; W converted in-block via LDS bounce ----------
__global__ __launch_bounds__(512) void dyn_kernel(
        const unsigned short* __restrict__ hbf, const float* __restrict__ emb,
        const float* __restrict__ w2, const float* __restrict__ b2,
        const float* __restrict__ x, const int* __restrict__ offsets,
        const int* __restrict__ sorted, float* __restrict__ out) {

    __shared__ alignas(16) unsigned short Wl[64 * PSTR];   // 80 KB  filter tile (bf16)
    __shared__ alignas(16) unsigned short Pl[NPC * PSTR];  // 40 KB  patches (bf16)
    __shared__ alignas(16) unsigned short Dl[NPC * 72];    //  4.5 KB intermediate
    __shared__ alignas(16) unsigned short w2l[64 * 72];    //  9 KB  1x1 weights bf16
    __shared__ float bias_l[64];
    __shared__ int pixs[NPC];

    int t = blockIdx.x;
    int start = offsets[t];
    int n = offsets[t + 1] - start;
    if (n <= 0) return;

    int tid  = threadIdx.x;
    int lane = tid & 63;
    int wv   = tid >> 6;
    int m    = wv & 3;          // M-tile (16 out channels)
    int ph   = wv >> 2;         // pixel half
    int ra   = lane & 15;
    int kg   = lane >> 4;

    const float* eb = emb + (size_t)t * 36928;

    // ---- cooperative W stage: coalesced f32 loads, f2bf, ds_write_b128 ----
    // 4608 units of 8 consecutive elements; unit u -> row r=u/72, col c0=(u%72)*8
    #pragma unroll
    for (int it = 0; it < 9; ++it) {
        int u  = tid + it * 512;
        int r  = u / 72;
        int c0 = (u - r * 72) * 8;
        const float* src = eb + r * ROWLEN + c0;
        f32x4u a = *(const f32x4u*)src;
        f32x4u b = *(const f32x4u*)(src + 4);
        u16x8 v;
        #pragma unroll
        for (int j = 0; j < 4; ++j) { v[j] = f2bf(a[j]); v[j + 4] = f2bf(b[j]); }
        *(u16x8*)&Wl[r * PSTR + (r & 7) * 8 + c0] = v;
    }
    if (tid < 64) bias_l[tid] = eb[tid * ROWLEN + KD];

    // stage w2 -> bf16 LDS (once)
    {
        int o = tid >> 3, i8 = (tid & 7) * 8;
        const float* src = w2 + o * 64 + i8;
        u16x8 v;
        #pragma unroll
        for (int j = 0; j < 8; ++j) v[j] = f2bf(src[j]);
        *(u16x8*)&w2l[o * 72 + i8] = v;
    }
    __syncthreads();   // W / w2 / bias ready

    // ---- pull W fragments into registers (once per block) ----
    int rowW = m * 16 + ra;
    const unsigned short* pW = Wl + rowW * PSTR + (rowW & 7) * 8 + kg * 8;
    u16x8 Wr[9][2];
    #pragma unroll
    for (int ck = 0; ck < 9; ++ck) {
        Wr[ck][0] = *(const u16x8*)(pW + ck * 64);
        Wr[ck][1] = *(const u16x8*)(pW + ck * 64 + 32);
    }
    int ob0 = m * 16 + kg * 4;
    float bias0 = bias_l[ob0 + 0], bias1 = bias_l[ob0 + 1];
    float bias2 = bias_l[ob0 + 2], bias3 = bias_l[ob0 + 3];

    const unsigned short* pB = Pl + (ph * 16 + ra) * PSTR + (ra & 7) * 8 + kg * 8;

    // gather roles
    int gp = tid >> 4;          // pixel 0..31
    int gk = tid & 15;
    unsigned short* pdst = Pl + gp * PSTR + (gp & 7) * 8;

    for (int base = 0; base < n; base += NPC) {
        __syncthreads();   // protect pixs/Pl/Dl from previous iteration's readers
        if (tid < NPC) pixs[tid] = (base + tid < n) ? sorted[start + base + tid] : -1;
        __syncthreads();

        // ---- stage full patch tile P[32 px][576 k] bf16 from hbf ----
        {
            int pixel = pixs[gp];
            int py = pixel >> 6, px = pixel & 63;
            #pragma unroll
            for (int pass = 0; pass < 9; ++pass) {
                int k0 = pass * 64 + gk * 4;
                u16x4 v;
                #pragma unroll
                for (int j = 0; j < 4; ++j) {
                    int k = k0 + j;
                    int cch = k / 9, r9 = k - cch * 9;
                    int dy = r9 / 3, dx = r9 - dy * 3;
                    unsigned short bits = 0;
                    if (pixel >= 0) {
                        int yy = py + dy - 1, xx = px + dx - 1;
                        if (yy >= 0 && yy < 64 && xx >= 0 && xx < 64)
                            bits = hbf[cch * 4096 + yy * 64 + xx];
                    }
                    v[j] = bits;
                }
                *(u16x4*)(pdst + k0) = v;
            }
        }
        __syncthreads();   // P ready

        // ---- K-loop: 18 ds_read_b128 + 18 MFMA, zero conversion ----
        f32x4 acc = {0.f, 0.f, 0.f, 0.f};
        #pragma unroll
        for (int ck = 0; ck < 9; ++ck) {
            #pragma unroll
            for (int ks = 0; ks < 2; ++ks) {
                u16x8 bv = *(const u16x8*)(pB + ck * 64 + ks * 32);
                acc = __builtin_amdgcn_mfma_f32_16x16x32_bf16(
                          __builtin_bit_cast(short8, Wr[ck][ks]),
                          __builtin_bit_cast(short8, bv), acc, 0, 0, 0);
            }
        }

        // ---- bias + relu -> Dl (bf16) ----
        {
            int pi = ph * 16 + ra;
            u16x4 dv;
            dv[0] = f2bf(fmaxf(acc[0] + bias0, 0.f));
            dv[1] = f2bf(fmaxf(acc[1] + bias1, 0.f));
            dv[2] = f2bf(fmaxf(acc[2] + bias2, 0.f));
            dv[3] = f2bf(fmaxf(acc[3] + bias3, 0.f));
            *(u16x4*)&Dl[pi * 72 + ob0] = dv;
        }
        __syncthreads();   // D ready

        // ---- GEMM2: 1x1 conv (K=64) ----
        f32x4 acc2 = {0.f, 0.f, 0.f, 0.f};
        #pragma unroll
        for (int ks = 0; ks < 2; ++ks) {
            u16x8 a2  = *(const u16x8*)&w2l[(m * 16 + ra) * 72 + ks * 32 + kg * 8];
            u16x8 b2v = *(const u16x8*)&Dl[(ph * 16 + ra) * 72 + ks * 32 + kg * 8];
            acc2 = __builtin_amdgcn_mfma_f32_16x16x32_bf16(
                       __builtin_bit_cast(short8, a2),
                       __builtin_bit_cast(short8, b2v), acc2, 0, 0, 0);
        }

        // ---- epilogue: + b2 + residual, relu, store ----
        {
            int pi = ph * 16 + ra;
            int pixel = pixs[pi];
            if (pixel >= 0) {
                #pragma unroll
                for (int j = 0; j < 4; ++j) {
                    int o = ob0 + j;
                    float v = acc2[j] + b2[o] + x[o * 4096 + pixel];
                    out[o * 4096 + pixel] = fmaxf(v, 0.f);
                }
            }
        }
    }
}

extern "C" void kernel_launch(void* const* d_in, const int* in_sizes, int n_in,
                              void* d_out, int out_size, void* d_ws, size_t ws_size,
                              hipStream_t stream) {
    const float* x       = (const float*)d_in[0];
    const int*   buckets = (const int*)d_in[1];
    const float* w1      = (const float*)d_in[2];
    const float* b1      = (const float*)d_in[3];
    const float* emb     = (const float*)d_in[4];
    const float* w2      = (const float*)d_in[5];
    const float* b2      = (const float*)d_in[6];
    float* out = (float*)d_out;

    char* ws = (char*)d_ws;
    unsigned short* hbf = (unsigned short*)ws;              // 512 KB
    int*   offsets      = (int*)(ws + (1 << 20));           // 217 ints
    int*   sorted       = (int*)(ws + (1 << 20) + 4096);    // 4096 ints

    prep_kernel<<<257, 256, 0, stream>>>(x, w1, b1, buckets, hbf, offsets, sorted);
    dyn_kernel<<<NTYPES, 512, 0, stream>>>(hbf, emb, w2, b2, x, offsets, sorted, out);
}